// Round 9
// baseline (233.844 us; speedup 1.0000x reference)
//
#include <hip/hip_runtime.h>
#include <math.h>

#define TOPK 2048
#define NCLS 80      // reference: randint(0, 80)
#define NT   256
#define NBIN 4096    // score-digest bins (uniform scores -> ~5/bin)
#define CMAX 2560    // candidate key capacity (K + tie-bin slack)
#define SMAX 20480   // LDS score-cache capacity (M = 20000 in reference)
#define K1B  32      // selection blocks (candidate partition by idx & 31)

struct SelP {
    const float* scores; const float* boxes; const int* classes;
    int M; int K;
    float4* sel_box; float* sel_score; int* sel_cls;
};

struct CmpP {
    const float4* sel_box; const float* sel_score; const int* sel_cls;
    const float* sw1; const float* sb1; const float* sw2; const float* sb2;
    const float* sw3; const float* sb3;
    const float* lw1; const float* lb1; const float* lw2; const float* lb2;
    int K;
    float* out_boxes; float* out_scores; float* out_cls;
};

__device__ __forceinline__ float iou_of(float xi, float yi, float ai,
                                        float x2i, float y2i, float4 bj) {
    float ix1 = fmaxf(xi, bj.x), iy1 = fmaxf(yi, bj.y);
    float ix2 = fminf(x2i, bj.x + bj.z), iy2 = fminf(y2i, bj.y + bj.w);
    float iw = fmaxf(ix2 - ix1, 0.0f), ih = fmaxf(iy2 - iy1, 0.0f);
    float inter = iw * ih;
    float uni = ai + bj.z * bj.w - inter;
    return inter / (uni + 1e-6f);
}

// monotone non-decreasing digest; single quantization used in all passes
__device__ __forceinline__ int digest12(float s) {
    int v = (int)(s * 4096.0f);
    return v < 0 ? 0 : (v > NBIN - 1 ? NBIN - 1 : v);
}

__device__ __forceinline__ float key_score(unsigned long long kk) {
    unsigned mono = (unsigned)(kk >> 32);
    unsigned ob = (mono & 0x80000000u) ? (mono & 0x7FFFFFFFu) : ~mono;
    return __uint_as_float(ob);
}

// ---------------------------------------------------------------------------
// k_sel: 32 blocks redundantly find the exact top-K (jax.lax.top_k stable
// semantics) via binned counting-rank, entirely in LDS after ONE global
// score sweep. Each block gathers+writes only candidates whose ORIGINAL
// index i satisfies (i & 31) == bid -- a deterministic disjoint partition,
// so the selected arrays in ws are written exactly once, no races.
// ---------------------------------------------------------------------------
__global__ __launch_bounds__(NT, 1) void k_sel(SelP p) {
    __shared__ float ssc[SMAX];                   // 80 KB score cache
    __shared__ int   bincur[NBIN];                // 16 KB count -> cursor
    __shared__ int   binbase[NBIN];               // 16 KB rank base
    __shared__ unsigned long long skeys[CMAX];    // 20 KB candidate keys
    __shared__ int   sfx[NT];
    __shared__ int   sh_cT;

    int tid = threadIdx.x, bid = blockIdx.x;
    int M = p.M, K = p.K, M4 = M >> 2;

    for (int b = tid; b < NBIN; b += NT) bincur[b] = 0;
    __syncthreads();

    // ---- sweep 1 (only global pass): cache scores in LDS + histogram ----
    const float4* s4p = (const float4*)p.scores;
    for (int base = 0; base < M4; base += NT * 4) {   // 4x ILP batching
        float4 v[4]; int ii[4];
        #pragma unroll
        for (int u = 0; u < 4; u++) {
            int i4 = base + u * NT + tid;
            ii[u] = (i4 < M4) ? i4 : -1;
            if (ii[u] >= 0) v[u] = s4p[i4];
        }
        #pragma unroll
        for (int u = 0; u < 4; u++) if (ii[u] >= 0) {
            if (ii[u] < SMAX / 4) ((float4*)ssc)[ii[u]] = v[u];
            atomicAdd(&bincur[digest12(v[u].x)], 1);
            atomicAdd(&bincur[digest12(v[u].y)], 1);
            atomicAdd(&bincur[digest12(v[u].z)], 1);
            atomicAdd(&bincur[digest12(v[u].w)], 1);
        }
    }
    for (int i = M4 * 4 + tid; i < M; i += NT) {
        float s = p.scores[i];
        if (i < SMAX) ssc[i] = s;
        atomicAdd(&bincur[digest12(s)], 1);
    }
    __syncthreads();

    // ---- suffix scan: binbase[b] = #elements with digest > b; find cT ----
    {
        const int BPT = NBIN / NT;                // 16 bins per thread
        int c0 = tid * BPT, sum = 0;
        #pragma unroll
        for (int u = 0; u < BPT; u++) sum += bincur[c0 + u];
        sfx[tid] = sum;
    }
    __syncthreads();
    for (int st = 1; st < NT; st <<= 1) {
        int v = (tid + st < NT) ? sfx[tid + st] : 0;
        __syncthreads(); sfx[tid] += v; __syncthreads();
    }
    {
        const int BPT = NBIN / NT;
        int running = (tid < NT - 1) ? sfx[tid + 1] : 0;
        int c0 = tid * BPT;
        for (int u = BPT - 1; u >= 0; u--) {
            int b = c0 + u, cnt = bincur[b];
            binbase[b] = running;
            if (running < K && running + cnt >= K) sh_cT = b;  // unique bin
            running += cnt;
        }
    }
    __syncthreads();
    int cT = sh_cT;
    for (int b = tid; b < NBIN; b += NT) bincur[b] = binbase[b];
    __syncthreads();

    // ---- sweep 2 (from LDS): scatter candidate keys into bin slots ----
    // key = monotonic(score bits) << 32 | (0xFFFFFFFF - i): descending key ==
    // descending score, ties -> lower index (stable top_k semantics).
    for (int i = tid; i < M; i += NT) {
        float s = (i < SMAX) ? ssc[i] : p.scores[i];
        int d = digest12(s);
        if (d >= cT) {
            int slot = atomicAdd(&bincur[d], 1);
            if (slot < CMAX) {
                unsigned b = __float_as_uint(s);
                b = (b & 0x80000000u) ? ~b : (b | 0x80000000u);
                skeys[slot] = ((unsigned long long)b << 32) |
                              (unsigned long long)(0xFFFFFFFFu - (unsigned)i);
            }
        }
    }
    __syncthreads();

    // ---- exact rank within bin + gather/write this block's partition ----
    {
        int C = bincur[cT]; if (C > CMAX) C = CMAX;
        const float4* boxes4 = (const float4*)p.boxes;
        for (int s = tid; s < C; s += NT) {
            unsigned long long ks = skeys[s];
            unsigned idx = 0xFFFFFFFFu - (unsigned)(ks & 0xFFFFFFFFull);
            if ((int)(idx & (K1B - 1)) != bid) continue;   // partition by index
            float sc = key_score(ks);
            int d = digest12(sc);
            int st = binbase[d], en = bincur[d]; if (en > CMAX) en = CMAX;
            int r = binbase[d];
            for (int t = st; t < en; t++) r += (skeys[t] > ks) ? 1 : 0;
            if (r < K) {
                p.sel_box[r] = boxes4[idx];
                p.sel_score[r] = sc;
                p.sel_cls[r] = p.classes[idx];
            }
        }
    }
}

// ---------------------------------------------------------------------------
// k_cmp: 512 blocks x 4 rows (one row per wave). Stages the 56 KB selected
// arrays (L2-hot) into LDS, builds class lists, computes D (unmasked IoU
// mean), S (same-class MLP suppression sum), lambda, and writes outputs.
// ---------------------------------------------------------------------------
__global__ __launch_bounds__(NT, 1) void k_cmp(CmpP p) {
    __shared__ float4 sbox[TOPK];                 // 32 KB
    __shared__ float  sscore[TOPK];               // 8 KB
    __shared__ short  scls[TOPK];                 // 4 KB
    __shared__ short  clist[TOPK];                // 4 KB
    __shared__ int    ccnt[NCLS], ccur[NCLS], cstart[NCLS + 1];
    __shared__ float  swt[914];                   // sup MLP 801 + lambda 113

    int tid = threadIdx.x, bid = blockIdx.x;
    int K = p.K;

    // ---- stage MLP weights ----
    for (int t = tid; t < 224; t += NT) swt[t] = p.sw1[t];
    if (tid < 32) swt[224 + tid] = p.sb1[tid];
    for (int t = tid; t < 512; t += NT) swt[256 + t] = p.sw2[t];
    if (tid < 16) swt[768 + tid] = p.sb2[tid];
    if (tid < 16) swt[784 + tid] = p.sw3[tid];
    if (tid == 0) swt[800] = p.sb3[0];
    if (tid < 80) swt[801 + tid] = p.lw1[tid];
    if (tid < 16) swt[881 + tid] = p.lb1[tid];
    if (tid < 16) swt[897 + tid] = p.lw2[tid];
    if (tid == 0) swt[913] = p.lb2[0];
    if (tid < NCLS) ccnt[tid] = 0;

    // ---- stage selected arrays (coalesced; L2-hot across 512 blocks) ----
    for (int r = tid; r < K; r += NT) {
        sbox[r] = p.sel_box[r];
        sscore[r] = p.sel_score[r];
        scls[r] = (short)p.sel_cls[r];
    }
    __syncthreads();

    // ---- per-class lists (order within class irrelevant: sums) ----
    for (int r = tid; r < K; r += NT) atomicAdd(&ccnt[scls[r]], 1);
    __syncthreads();
    if (tid == 0) {
        int acc = 0;
        for (int c = 0; c < NCLS; c++) { cstart[c] = acc; ccur[c] = acc; acc += ccnt[c]; }
        cstart[NCLS] = acc;
    }
    __syncthreads();
    for (int r = tid; r < K; r += NT) {
        int pos = atomicAdd(&ccur[scls[r]], 1);
        clist[pos] = (short)r;
    }
    __syncthreads();

    const float* W1 = swt;       const float* B1 = swt + 224;
    const float* W2 = swt + 256; const float* B2 = swt + 768;
    const float* W3 = swt + 784; float B3 = swt[800];

    int g = tid >> 6, lane = tid & 63;
    int r = bid * 4 + g;
    if (r >= K) return;
    float4 bi = sbox[r];
    float ai = bi.z * bi.w, x2i = bi.x + bi.z, y2i = bi.y + bi.w;

    // Phase A: unmasked IoU row mean over all K
    float dsum = 0.0f;
    for (int j = lane; j < K; j += 64)
        dsum += iou_of(bi.x, bi.y, ai, x2i, y2i, sbox[j]);
    #pragma unroll
    for (int off = 32; off >= 1; off >>= 1) dsum += __shfl_xor(dsum, off, 64);
    float D = dsum / (float)K;

    // Phase B: suppression sum over same-class list (~K/NCLS entries)
    float si = sscore[r];
    int c = scls[r];
    int cs = cstart[c], ce = cstart[c + 1];
    float ssum = 0.0f;
    for (int t = cs + lane; t < ce; t += 64) {
        int j = clist[t];
        float4 bj = sbox[j];
        float iou = iou_of(bi.x, bi.y, ai, x2i, y2i, bj);
        float f1 = fabsf(bi.x - bj.x), f2 = fabsf(bi.y - bj.y);
        float f3 = fabsf(bi.z - bj.z), f4 = fabsf(bi.w - bj.w);
        float f6 = sscore[j];
        float h[32];
        #pragma unroll
        for (int o = 0; o < 32; o++) {
            float a = B1[o];
            a += iou * W1[0 * 32 + o];
            a += f1 * W1[1 * 32 + o];
            a += f2 * W1[2 * 32 + o];
            a += f3 * W1[3 * 32 + o];
            a += f4 * W1[4 * 32 + o];
            a += si * W1[5 * 32 + o];
            a += f6 * W1[6 * 32 + o];
            h[o] = fmaxf(a, 0.0f);
        }
        float acc3 = B3;
        #pragma unroll
        for (int q = 0; q < 16; q++) {
            float a = B2[q];
            #pragma unroll
            for (int o = 0; o < 32; o++) a += h[o] * W2[o * 16 + q];
            acc3 += fmaxf(a, 0.0f) * W3[q];
        }
        ssum += iou / (1.0f + expf(-acc3));
    }
    #pragma unroll
    for (int off = 32; off >= 1; off >>= 1) ssum += __shfl_xor(ssum, off, 64);

    if (lane == 0) {
        // lambda MLP: sigmoid(relu([x,y,w,h,s]@lw1+lb1)@lw2+lb2)
        const float* LW1 = swt + 801; const float* LB1 = swt + 881;
        const float* LW2 = swt + 897; float LB2 = swt[913];
        float in5[5] = { bi.x, bi.y, bi.z, bi.w, si };
        float acc = LB2;
        #pragma unroll
        for (int o = 0; o < 16; o++) {
            float a2 = LB1[o];
            #pragma unroll
            for (int f = 0; f < 5; f++) a2 += in5[f] * LW1[f * 16 + o];
            acc += fmaxf(a2, 0.0f) * LW2[o];
        }
        float lam = 1.0f / (1.0f + expf(-acc));
        ((float4*)p.out_boxes)[r] = bi;
        p.out_cls[r] = (float)c;
        p.out_scores[r] = si * expf(-lam * ssum * D);
    }
}

extern "C" void kernel_launch(void* const* d_in, const int* in_sizes, int n_in,
                              void* d_out, int out_size, void* d_ws, size_t ws_size,
                              hipStream_t stream) {
    int M = in_sizes[1];
    int K = (M < TOPK) ? M : TOPK;

    char* ws = (char*)d_ws;
    float4* sel_box  = (float4*)ws;            ws += (size_t)TOPK * 16;
    float*  sel_score = (float*)ws;            ws += (size_t)TOPK * 4;
    int*    sel_cls   = (int*)ws;              ws += (size_t)TOPK * 4;

    SelP sp;
    sp.scores  = (const float*)d_in[1];
    sp.boxes   = (const float*)d_in[0];
    sp.classes = (const int*)d_in[2];
    sp.M = M; sp.K = K;
    sp.sel_box = sel_box; sp.sel_score = sel_score; sp.sel_cls = sel_cls;

    CmpP cp;
    cp.sel_box = sel_box; cp.sel_score = sel_score; cp.sel_cls = sel_cls;
    cp.sw1 = (const float*)d_in[3];  cp.sb1 = (const float*)d_in[4];
    cp.sw2 = (const float*)d_in[5];  cp.sb2 = (const float*)d_in[6];
    cp.sw3 = (const float*)d_in[7];  cp.sb3 = (const float*)d_in[8];
    cp.lw1 = (const float*)d_in[9];  cp.lb1 = (const float*)d_in[10];
    cp.lw2 = (const float*)d_in[11]; cp.lb2 = (const float*)d_in[12];
    cp.K = K;
    cp.out_boxes  = (float*)d_out;
    cp.out_scores = (float*)d_out + (size_t)K * 4;
    cp.out_cls    = (float*)d_out + (size_t)K * 5;

    k_sel<<<K1B, NT, 0, stream>>>(sp);
    k_cmp<<<(K + 3) / 4, NT, 0, stream>>>(cp);
}

// Round 10
// 128.881 us; speedup vs baseline: 1.8144x; 1.8144x over previous
//
#include <hip/hip_runtime.h>
#include <math.h>

#define TOPK 2048
#define NCLS 80      // reference: randint(0, 80)
#define NBIN 4096    // score-digest bins (uniform scores -> ~5/bin)
#define CMAX 2560    // candidate key capacity (K + tie-bin slack)
#define SMAX 20480   // LDS score-cache capacity (M = 20000 in reference)
#define K1B  32      // selection blocks (candidate partition by idx & 31)
#define STN  512     // k_sel threads (8 waves -> latency hiding)
#define CTN  256     // k_cmp threads
#define CROWS 16     // k_cmp rows per block -> 128 blocks

struct SelP {
    const float* scores; const float* boxes; const int* classes;
    int M; int K;
    float4* sel_box; float* sel_score; int* sel_cls;
};

struct CmpP {
    const float4* sel_box; const float* sel_score; const int* sel_cls;
    const float* sw1; const float* sb1; const float* sw2; const float* sb2;
    const float* sw3; const float* sb3;
    const float* lw1; const float* lb1; const float* lw2; const float* lb2;
    int K;
    float* out_boxes; float* out_scores; float* out_cls;
};

__device__ __forceinline__ float iou_of(float xi, float yi, float ai,
                                        float x2i, float y2i, float4 bj) {
    float ix1 = fmaxf(xi, bj.x), iy1 = fmaxf(yi, bj.y);
    float ix2 = fminf(x2i, bj.x + bj.z), iy2 = fminf(y2i, bj.y + bj.w);
    float iw = fmaxf(ix2 - ix1, 0.0f), ih = fmaxf(iy2 - iy1, 0.0f);
    float inter = iw * ih;
    float uni = ai + bj.z * bj.w - inter;
    return inter / (uni + 1e-6f);
}

// monotone non-decreasing digest; single quantization used in all passes
__device__ __forceinline__ int digest12(float s) {
    int v = (int)(s * 4096.0f);
    return v < 0 ? 0 : (v > NBIN - 1 ? NBIN - 1 : v);
}

__device__ __forceinline__ float key_score(unsigned long long kk) {
    unsigned mono = (unsigned)(kk >> 32);
    unsigned ob = (mono & 0x80000000u) ? (mono & 0x7FFFFFFFu) : ~mono;
    return __uint_as_float(ob);
}

// ---------------------------------------------------------------------------
// k_sel: 32 blocks redundantly find the exact top-K (jax.lax.top_k stable
// semantics) via binned counting-rank, entirely in LDS after ONE global
// score sweep. Each block gathers+writes only candidates whose ORIGINAL
// index satisfies (idx & 31) == bid -- deterministic disjoint partition.
// ---------------------------------------------------------------------------
__global__ __launch_bounds__(STN, 1) void k_sel(SelP p) {
    __shared__ float ssc[SMAX];                   // 80 KB score cache
    __shared__ int   bincur[NBIN];                // 16 KB count -> cursor
    __shared__ int   binbase[NBIN];               // 16 KB rank base
    __shared__ unsigned long long skeys[CMAX];    // 20 KB candidate keys
    __shared__ int   sfx[STN];
    __shared__ int   sh_cT;

    int tid = threadIdx.x, bid = blockIdx.x;
    int M = p.M, K = p.K, M4 = M >> 2;

    for (int b = tid; b < NBIN; b += STN) bincur[b] = 0;
    __syncthreads();

    // ---- sweep 1 (the only full global pass): cache scores + histogram ----
    const float4* s4p = (const float4*)p.scores;
    for (int i4 = tid; i4 < M4; i4 += STN) {
        float4 v = s4p[i4];
        if (i4 < SMAX / 4) ((float4*)ssc)[i4] = v;
        atomicAdd(&bincur[digest12(v.x)], 1);
        atomicAdd(&bincur[digest12(v.y)], 1);
        atomicAdd(&bincur[digest12(v.z)], 1);
        atomicAdd(&bincur[digest12(v.w)], 1);
    }
    for (int i = M4 * 4 + tid; i < M; i += STN) {
        float s = p.scores[i];
        if (i < SMAX) ssc[i] = s;
        atomicAdd(&bincur[digest12(s)], 1);
    }
    __syncthreads();

    // ---- suffix scan: binbase[b] = #elements with digest > b; find cT ----
    {
        const int BPT = NBIN / STN;               // 8 bins per thread
        int c0 = tid * BPT, sum = 0;
        #pragma unroll
        for (int u = 0; u < BPT; u++) sum += bincur[c0 + u];
        sfx[tid] = sum;
    }
    __syncthreads();
    for (int st = 1; st < STN; st <<= 1) {
        int v = (tid + st < STN) ? sfx[tid + st] : 0;
        __syncthreads(); sfx[tid] += v; __syncthreads();
    }
    {
        const int BPT = NBIN / STN;
        int running = (tid < STN - 1) ? sfx[tid + 1] : 0;
        int c0 = tid * BPT;
        for (int u = BPT - 1; u >= 0; u--) {
            int b = c0 + u, cnt = bincur[b];
            binbase[b] = running;
            if (running < K && running + cnt >= K) sh_cT = b;  // unique bin
            running += cnt;
        }
    }
    __syncthreads();
    int cT = sh_cT;
    for (int b = tid; b < NBIN; b += STN) bincur[b] = binbase[b];
    __syncthreads();

    // ---- sweep 2 (from LDS): scatter candidate keys into bin slots ----
    // key = monotonic(score bits) << 32 | (0xFFFFFFFF - i): descending key ==
    // descending score, ties -> lower index (stable top_k semantics).
    for (int i = tid; i < M; i += STN) {
        float s = (i < SMAX) ? ssc[i] : p.scores[i];
        int d = digest12(s);
        if (d >= cT) {
            int slot = atomicAdd(&bincur[d], 1);
            if (slot < CMAX) {
                unsigned b = __float_as_uint(s);
                b = (b & 0x80000000u) ? ~b : (b | 0x80000000u);
                skeys[slot] = ((unsigned long long)b << 32) |
                              (unsigned long long)(0xFFFFFFFFu - (unsigned)i);
            }
        }
    }
    __syncthreads();

    // ---- exact rank within bin (~5 peers) + gather/write own partition ----
    {
        int C = bincur[cT]; if (C > CMAX) C = CMAX;
        const float4* boxes4 = (const float4*)p.boxes;
        for (int s = tid; s < C; s += STN) {
            unsigned long long ks = skeys[s];
            unsigned idx = 0xFFFFFFFFu - (unsigned)(ks & 0xFFFFFFFFull);
            if ((int)(idx & (K1B - 1)) != bid) continue;   // partition by index
            float sc = key_score(ks);
            int d = digest12(sc);
            int st = binbase[d], en = bincur[d]; if (en > CMAX) en = CMAX;
            int r = binbase[d];
            for (int t = st; t < en; t++) r += (skeys[t] > ks) ? 1 : 0;
            if (r < K) {
                p.sel_box[r] = boxes4[idx];
                p.sel_score[r] = sc;
                p.sel_cls[r] = p.classes[idx];
            }
        }
    }
}

// ---------------------------------------------------------------------------
// k_cmp: 128 blocks x 16 rows. Stages the 56 KB selected arrays (contiguous)
// into LDS once per block, builds class lists, computes D (unmasked IoU
// mean, 16 threads/row), S (flat per-pair MLP, ~1.6 MLP/thread), lambda,
// and writes this block's outputs.
// ---------------------------------------------------------------------------
__global__ __launch_bounds__(CTN, 1) void k_cmp(CmpP p) {
    __shared__ float4 sbox[TOPK];                 // 32 KB
    __shared__ float  sscore[TOPK];               // 8 KB
    __shared__ short  scls[TOPK];                 // 4 KB
    __shared__ short  clist[TOPK];                // 4 KB
    __shared__ int    ccnt[NCLS], ccur[NCLS], cstart[NCLS + 1];
    __shared__ float  swt[914];                   // sup MLP 801 + lambda 113
    __shared__ int    prefix[CROWS + 1];
    __shared__ int    rowcs[CROWS];
    __shared__ float  Ssum[CROWS], Drow[CROWS];

    int tid = threadIdx.x, bid = blockIdx.x;
    int K = p.K;

    // ---- stage MLP weights ----
    for (int t = tid; t < 224; t += CTN) swt[t] = p.sw1[t];
    if (tid < 32) swt[224 + tid] = p.sb1[tid];
    for (int t = tid; t < 512; t += CTN) swt[256 + t] = p.sw2[t];
    if (tid < 16) swt[768 + tid] = p.sb2[tid];
    if (tid < 16) swt[784 + tid] = p.sw3[tid];
    if (tid == 0) swt[800] = p.sb3[0];
    if (tid < 80) swt[801 + tid] = p.lw1[tid];
    if (tid < 16) swt[881 + tid] = p.lb1[tid];
    if (tid < 16) swt[897 + tid] = p.lw2[tid];
    if (tid == 0) swt[913] = p.lb2[0];
    if (tid < NCLS) ccnt[tid] = 0;

    // ---- stage selected arrays (contiguous, coalesced) ----
    for (int r = tid; r < K; r += CTN) {
        sbox[r] = p.sel_box[r];
        sscore[r] = p.sel_score[r];
        scls[r] = (short)p.sel_cls[r];
    }
    __syncthreads();

    // ---- per-class lists (order within class irrelevant: sums) ----
    for (int r = tid; r < K; r += CTN) atomicAdd(&ccnt[scls[r]], 1);
    __syncthreads();
    if (tid == 0) {
        int acc = 0;
        for (int c = 0; c < NCLS; c++) { cstart[c] = acc; ccur[c] = acc; acc += ccnt[c]; }
        cstart[NCLS] = acc;
    }
    __syncthreads();
    for (int r = tid; r < K; r += CTN) {
        int pos = atomicAdd(&ccur[scls[r]], 1);
        clist[pos] = (short)r;
    }

    int r0 = bid * CROWS;
    int nrows = K - r0; if (nrows > CROWS) nrows = CROWS;
    if (nrows <= 0) return;
    if (tid < nrows) Ssum[tid] = 0.0f;
    __syncthreads();

    // ---- Phase A: D row means; 16 threads/row, 128 cols each ----
    {
        int row = tid >> 4, sub = tid & 15;
        if (row < nrows) {
            float4 bi = sbox[r0 + row];
            float ai = bi.z * bi.w, x2i = bi.x + bi.z, y2i = bi.y + bi.w;
            float dsum = 0.0f;
            for (int j = sub; j < K; j += 16)
                dsum += iou_of(bi.x, bi.y, ai, x2i, y2i, sbox[j]);
            // reduce within the 16-lane group (xor offsets stay in-group)
            #pragma unroll
            for (int off = 8; off >= 1; off >>= 1)
                dsum += __shfl_xor(dsum, off, 64);
            if (sub == 0) Drow[row] = dsum / (float)K;
        }
    }

    // ---- per-row pair prefix (same-class peer counts) ----
    if (tid == 0) {
        int acc = 0;
        for (int rr = 0; rr < nrows; rr++) {
            int c = scls[r0 + rr];
            prefix[rr] = acc;
            rowcs[rr] = cstart[c];
            acc += ccnt[c];
        }
        prefix[nrows] = acc;
    }
    __syncthreads();
    int Pb = prefix[nrows];

    const float* W1 = swt;       const float* B1 = swt + 224;
    const float* W2 = swt + 256; const float* B2 = swt + 768;
    const float* W3 = swt + 784; float B3 = swt[800];

    // ---- Phase B: flat per-pair MLP, full lane utilization ----
    for (int pp = tid; pp < Pb; pp += CTN) {
        int lo = 0, hi = nrows;
        while (hi - lo > 1) {
            int mid = (lo + hi) >> 1;
            if (prefix[mid] <= pp) lo = mid; else hi = mid;
        }
        int row = lo;
        int j = clist[rowcs[row] + (pp - prefix[row])];
        float4 bi = sbox[r0 + row], bj = sbox[j];
        float ai = bi.z * bi.w, x2i = bi.x + bi.z, y2i = bi.y + bi.w;
        float iou = iou_of(bi.x, bi.y, ai, x2i, y2i, bj);
        float f1 = fabsf(bi.x - bj.x), f2 = fabsf(bi.y - bj.y);
        float f3 = fabsf(bi.z - bj.z), f4 = fabsf(bi.w - bj.w);
        float f5 = sscore[r0 + row], f6 = sscore[j];
        float h[32];
        #pragma unroll
        for (int o = 0; o < 32; o++) {
            float a = B1[o];
            a += iou * W1[0 * 32 + o];
            a += f1 * W1[1 * 32 + o];
            a += f2 * W1[2 * 32 + o];
            a += f3 * W1[3 * 32 + o];
            a += f4 * W1[4 * 32 + o];
            a += f5 * W1[5 * 32 + o];
            a += f6 * W1[6 * 32 + o];
            h[o] = fmaxf(a, 0.0f);
        }
        float acc3 = B3;
        #pragma unroll
        for (int q = 0; q < 16; q++) {
            float a = B2[q];
            #pragma unroll
            for (int o = 0; o < 32; o++) a += h[o] * W2[o * 16 + q];
            acc3 += fmaxf(a, 0.0f) * W3[q];
        }
        atomicAdd(&Ssum[row], iou / (1.0f + expf(-acc3)));
    }
    __syncthreads();

    // ---- finale: lambda MLP + outputs for this block's rows ----
    if (tid < nrows) {
        int r = r0 + tid;
        float4 bi = sbox[r];
        float si = sscore[r];
        const float* LW1 = swt + 801; const float* LB1 = swt + 881;
        const float* LW2 = swt + 897; float LB2 = swt[913];
        float in5[5] = { bi.x, bi.y, bi.z, bi.w, si };
        float acc = LB2;
        #pragma unroll
        for (int o = 0; o < 16; o++) {
            float a2 = LB1[o];
            #pragma unroll
            for (int f = 0; f < 5; f++) a2 += in5[f] * LW1[f * 16 + o];
            acc += fmaxf(a2, 0.0f) * LW2[o];
        }
        float lam = 1.0f / (1.0f + expf(-acc));
        ((float4*)p.out_boxes)[r] = bi;
        p.out_cls[r] = (float)scls[r];
        p.out_scores[r] = si * expf(-lam * Ssum[tid] * Drow[tid]);
    }
}

extern "C" void kernel_launch(void* const* d_in, const int* in_sizes, int n_in,
                              void* d_out, int out_size, void* d_ws, size_t ws_size,
                              hipStream_t stream) {
    int M = in_sizes[1];
    int K = (M < TOPK) ? M : TOPK;

    char* ws = (char*)d_ws;
    float4* sel_box   = (float4*)ws;           ws += (size_t)TOPK * 16;
    float*  sel_score = (float*)ws;            ws += (size_t)TOPK * 4;
    int*    sel_cls   = (int*)ws;              ws += (size_t)TOPK * 4;

    SelP sp;
    sp.scores  = (const float*)d_in[1];
    sp.boxes   = (const float*)d_in[0];
    sp.classes = (const int*)d_in[2];
    sp.M = M; sp.K = K;
    sp.sel_box = sel_box; sp.sel_score = sel_score; sp.sel_cls = sel_cls;

    CmpP cp;
    cp.sel_box = sel_box; cp.sel_score = sel_score; cp.sel_cls = sel_cls;
    cp.sw1 = (const float*)d_in[3];  cp.sb1 = (const float*)d_in[4];
    cp.sw2 = (const float*)d_in[5];  cp.sb2 = (const float*)d_in[6];
    cp.sw3 = (const float*)d_in[7];  cp.sb3 = (const float*)d_in[8];
    cp.lw1 = (const float*)d_in[9];  cp.lb1 = (const float*)d_in[10];
    cp.lw2 = (const float*)d_in[11]; cp.lb2 = (const float*)d_in[12];
    cp.K = K;
    cp.out_boxes  = (float*)d_out;
    cp.out_scores = (float*)d_out + (size_t)K * 4;
    cp.out_cls    = (float*)d_out + (size_t)K * 5;

    k_sel<<<K1B, STN, 0, stream>>>(sp);
    k_cmp<<<(K + CROWS - 1) / CROWS, CTN, 0, stream>>>(cp);
}

// Round 11
// 112.581 us; speedup vs baseline: 2.0771x; 1.1448x over previous
//
#include <hip/hip_runtime.h>
#include <math.h>

#define TOPK 2048
#define NCLS 80      // reference: randint(0, 80)
#define NBIN 4096    // score-digest bins (uniform scores -> ~5/bin)
#define CMAX 2560    // candidate key capacity (K + tie-bin slack)
#define SMAX 20480   // LDS score-cache capacity (M = 20000 in reference)
#define K1B  32      // selection blocks (candidate partition by idx & 31)
#define STN  1024    // k_sel threads (16 waves -> short loops + hiding)
#define CTN  256     // k_cmp threads
#define CROWS 8      // k_cmp rows per block -> 256 blocks (1 per CU)

struct SelP {
    const float* scores; const float* boxes; const int* classes;
    int M; int K;
    float4* sel_box; float* sel_score; int* sel_cls;
};

struct CmpP {
    const float4* sel_box; const float* sel_score; const int* sel_cls;
    const float* sw1; const float* sb1; const float* sw2; const float* sb2;
    const float* sw3; const float* sb3;
    const float* lw1; const float* lb1; const float* lw2; const float* lb2;
    int K;
    float* out_boxes; float* out_scores; float* out_cls;
};

__device__ __forceinline__ float iou_of(float xi, float yi, float ai,
                                        float x2i, float y2i, float4 bj) {
    float ix1 = fmaxf(xi, bj.x), iy1 = fmaxf(yi, bj.y);
    float ix2 = fminf(x2i, bj.x + bj.z), iy2 = fminf(y2i, bj.y + bj.w);
    float iw = fmaxf(ix2 - ix1, 0.0f), ih = fmaxf(iy2 - iy1, 0.0f);
    float inter = iw * ih;
    float uni = ai + bj.z * bj.w - inter;
    return inter / (uni + 1e-6f);
}

// monotone non-decreasing digest; single quantization used in all passes
__device__ __forceinline__ int digest12(float s) {
    int v = (int)(s * 4096.0f);
    return v < 0 ? 0 : (v > NBIN - 1 ? NBIN - 1 : v);
}

__device__ __forceinline__ float key_score(unsigned long long kk) {
    unsigned mono = (unsigned)(kk >> 32);
    unsigned ob = (mono & 0x80000000u) ? (mono & 0x7FFFFFFFu) : ~mono;
    return __uint_as_float(ob);
}

// ---------------------------------------------------------------------------
// k_sel: 32 blocks redundantly find the exact top-K (jax.lax.top_k stable
// semantics) via binned counting-rank, entirely in LDS after ONE global
// score sweep. Each block gathers+writes only candidates whose ORIGINAL
// index satisfies (idx & 31) == bid -- deterministic disjoint partition.
// ---------------------------------------------------------------------------
__global__ __launch_bounds__(STN, 1) void k_sel(SelP p) {
    __shared__ float ssc[SMAX];                   // 80 KB score cache
    __shared__ int   bincur[NBIN];                // 16 KB count -> cursor
    __shared__ int   binbase[NBIN];               // 16 KB rank base
    __shared__ unsigned long long skeys[CMAX];    // 20 KB candidate keys
    __shared__ int   sfx[STN];                    // 4 KB
    __shared__ int   sh_cT;

    int tid = threadIdx.x, bid = blockIdx.x;
    int M = p.M, K = p.K, M4 = M >> 2;

    for (int b = tid; b < NBIN; b += STN) bincur[b] = 0;
    __syncthreads();

    // ---- sweep 1 (the only full global pass): cache scores + histogram ----
    const float4* s4p = (const float4*)p.scores;
    for (int i4 = tid; i4 < M4; i4 += STN) {
        float4 v = s4p[i4];
        if (i4 < SMAX / 4) ((float4*)ssc)[i4] = v;
        atomicAdd(&bincur[digest12(v.x)], 1);
        atomicAdd(&bincur[digest12(v.y)], 1);
        atomicAdd(&bincur[digest12(v.z)], 1);
        atomicAdd(&bincur[digest12(v.w)], 1);
    }
    for (int i = M4 * 4 + tid; i < M; i += STN) {
        float s = p.scores[i];
        if (i < SMAX) ssc[i] = s;
        atomicAdd(&bincur[digest12(s)], 1);
    }
    __syncthreads();

    // ---- suffix scan: binbase[b] = #elements with digest > b; find cT ----
    {
        const int BPT = NBIN / STN;               // 4 bins per thread
        int c0 = tid * BPT, sum = 0;
        #pragma unroll
        for (int u = 0; u < BPT; u++) sum += bincur[c0 + u];
        sfx[tid] = sum;
    }
    __syncthreads();
    for (int st = 1; st < STN; st <<= 1) {
        int v = (tid + st < STN) ? sfx[tid + st] : 0;
        __syncthreads(); sfx[tid] += v; __syncthreads();
    }
    {
        const int BPT = NBIN / STN;
        int running = (tid < STN - 1) ? sfx[tid + 1] : 0;
        int c0 = tid * BPT;
        for (int u = BPT - 1; u >= 0; u--) {
            int b = c0 + u, cnt = bincur[b];
            binbase[b] = running;
            if (running < K && running + cnt >= K) sh_cT = b;  // unique bin
            running += cnt;
        }
    }
    __syncthreads();
    int cT = sh_cT;
    for (int b = tid; b < NBIN; b += STN) bincur[b] = binbase[b];
    __syncthreads();

    // ---- sweep 2 (from LDS): scatter candidate keys into bin slots ----
    // key = monotonic(score bits) << 32 | (0xFFFFFFFF - i): descending key ==
    // descending score, ties -> lower index (stable top_k semantics).
    for (int i = tid; i < M; i += STN) {
        float s = (i < SMAX) ? ssc[i] : p.scores[i];
        int d = digest12(s);
        if (d >= cT) {
            int slot = atomicAdd(&bincur[d], 1);
            if (slot < CMAX) {
                unsigned b = __float_as_uint(s);
                b = (b & 0x80000000u) ? ~b : (b | 0x80000000u);
                skeys[slot] = ((unsigned long long)b << 32) |
                              (unsigned long long)(0xFFFFFFFFu - (unsigned)i);
            }
        }
    }
    __syncthreads();

    // ---- exact rank within bin (~5 peers) + gather/write own partition ----
    {
        int C = bincur[cT]; if (C > CMAX) C = CMAX;
        const float4* boxes4 = (const float4*)p.boxes;
        for (int s = tid; s < C; s += STN) {
            unsigned long long ks = skeys[s];
            unsigned idx = 0xFFFFFFFFu - (unsigned)(ks & 0xFFFFFFFFull);
            if ((int)(idx & (K1B - 1)) != bid) continue;   // partition by index
            float sc = key_score(ks);
            int d = digest12(sc);
            int st = binbase[d], en = bincur[d]; if (en > CMAX) en = CMAX;
            int r = binbase[d];
            for (int t = st; t < en; t++) r += (skeys[t] > ks) ? 1 : 0;
            if (r < K) {
                p.sel_box[r] = boxes4[idx];
                p.sel_score[r] = sc;
                p.sel_cls[r] = p.classes[idx];
            }
        }
    }
}

// ---------------------------------------------------------------------------
// k_cmp: 256 blocks x 8 rows (one block per CU). Stages the 56 KB selected
// arrays into LDS once per block, builds class lists, computes D (unmasked
// IoU mean, 32 threads/row), S (flat per-pair MLP, ~0.8 MLP/thread),
// lambda, and writes this block's outputs.
// ---------------------------------------------------------------------------
__global__ __launch_bounds__(CTN, 1) void k_cmp(CmpP p) {
    __shared__ float4 sbox[TOPK];                 // 32 KB
    __shared__ float  sscore[TOPK];               // 8 KB
    __shared__ short  scls[TOPK];                 // 4 KB
    __shared__ short  clist[TOPK];                // 4 KB
    __shared__ int    ccnt[NCLS], ccur[NCLS], cstart[NCLS + 1];
    __shared__ float  swt[914];                   // sup MLP 801 + lambda 113
    __shared__ int    prefix[CROWS + 1];
    __shared__ int    rowcs[CROWS];
    __shared__ float  Ssum[CROWS], Drow[CROWS];

    int tid = threadIdx.x, bid = blockIdx.x;
    int K = p.K;

    // ---- stage selected arrays first (longest-latency loads) ----
    for (int r = tid; r < K; r += CTN) {
        sbox[r] = p.sel_box[r];
        sscore[r] = p.sel_score[r];
        scls[r] = (short)p.sel_cls[r];
    }

    // ---- stage MLP weights ----
    for (int t = tid; t < 224; t += CTN) swt[t] = p.sw1[t];
    if (tid < 32) swt[224 + tid] = p.sb1[tid];
    for (int t = tid; t < 512; t += CTN) swt[256 + t] = p.sw2[t];
    if (tid < 16) swt[768 + tid] = p.sb2[tid];
    if (tid < 16) swt[784 + tid] = p.sw3[tid];
    if (tid == 0) swt[800] = p.sb3[0];
    if (tid < 80) swt[801 + tid] = p.lw1[tid];
    if (tid < 16) swt[881 + tid] = p.lb1[tid];
    if (tid < 16) swt[897 + tid] = p.lw2[tid];
    if (tid == 0) swt[913] = p.lb2[0];
    if (tid < NCLS) ccnt[tid] = 0;
    __syncthreads();

    // ---- per-class lists (order within class irrelevant: sums) ----
    for (int r = tid; r < K; r += CTN) atomicAdd(&ccnt[scls[r]], 1);
    __syncthreads();
    if (tid == 0) {
        int acc = 0;
        for (int c = 0; c < NCLS; c++) { cstart[c] = acc; ccur[c] = acc; acc += ccnt[c]; }
        cstart[NCLS] = acc;
    }
    __syncthreads();
    for (int r = tid; r < K; r += CTN) {
        int pos = atomicAdd(&ccur[scls[r]], 1);
        clist[pos] = (short)r;
    }

    int r0 = bid * CROWS;
    int nrows = K - r0; if (nrows > CROWS) nrows = CROWS;
    if (nrows <= 0) return;
    if (tid < nrows) Ssum[tid] = 0.0f;
    __syncthreads();

    // ---- Phase A: D row means; 32 threads/row, 64 cols each ----
    {
        int row = tid >> 5, sub = tid & 31;
        if (row < nrows) {
            float4 bi = sbox[r0 + row];
            float ai = bi.z * bi.w, x2i = bi.x + bi.z, y2i = bi.y + bi.w;
            float dsum = 0.0f;
            for (int j = sub; j < K; j += 32)
                dsum += iou_of(bi.x, bi.y, ai, x2i, y2i, sbox[j]);
            // reduce within the 32-lane group (xor offsets stay in-group)
            #pragma unroll
            for (int off = 16; off >= 1; off >>= 1)
                dsum += __shfl_xor(dsum, off, 64);
            if (sub == 0) Drow[row] = dsum / (float)K;
        }
    }

    // ---- per-row pair prefix (same-class peer counts) ----
    if (tid == 0) {
        int acc = 0;
        for (int rr = 0; rr < nrows; rr++) {
            int c = scls[r0 + rr];
            prefix[rr] = acc;
            rowcs[rr] = cstart[c];
            acc += ccnt[c];
        }
        prefix[nrows] = acc;
    }
    __syncthreads();
    int Pb = prefix[nrows];

    const float* W1 = swt;       const float* B1 = swt + 224;
    const float* W2 = swt + 256; const float* B2 = swt + 768;
    const float* W3 = swt + 784; float B3 = swt[800];

    // ---- Phase B: flat per-pair MLP, full lane utilization ----
    for (int pp = tid; pp < Pb; pp += CTN) {
        int lo = 0, hi = nrows;
        while (hi - lo > 1) {
            int mid = (lo + hi) >> 1;
            if (prefix[mid] <= pp) lo = mid; else hi = mid;
        }
        int row = lo;
        int j = clist[rowcs[row] + (pp - prefix[row])];
        float4 bi = sbox[r0 + row], bj = sbox[j];
        float ai = bi.z * bi.w, x2i = bi.x + bi.z, y2i = bi.y + bi.w;
        float iou = iou_of(bi.x, bi.y, ai, x2i, y2i, bj);
        float f1 = fabsf(bi.x - bj.x), f2 = fabsf(bi.y - bj.y);
        float f3 = fabsf(bi.z - bj.z), f4 = fabsf(bi.w - bj.w);
        float f5 = sscore[r0 + row], f6 = sscore[j];
        float h[32];
        #pragma unroll
        for (int o = 0; o < 32; o++) {
            float a = B1[o];
            a += iou * W1[0 * 32 + o];
            a += f1 * W1[1 * 32 + o];
            a += f2 * W1[2 * 32 + o];
            a += f3 * W1[3 * 32 + o];
            a += f4 * W1[4 * 32 + o];
            a += f5 * W1[5 * 32 + o];
            a += f6 * W1[6 * 32 + o];
            h[o] = fmaxf(a, 0.0f);
        }
        float acc3 = B3;
        #pragma unroll
        for (int q = 0; q < 16; q++) {
            float a = B2[q];
            #pragma unroll
            for (int o = 0; o < 32; o++) a += h[o] * W2[o * 16 + q];
            acc3 += fmaxf(a, 0.0f) * W3[q];
        }
        atomicAdd(&Ssum[row], iou / (1.0f + expf(-acc3)));
    }
    __syncthreads();

    // ---- finale: lambda MLP + outputs for this block's rows ----
    if (tid < nrows) {
        int r = r0 + tid;
        float4 bi = sbox[r];
        float si = sscore[r];
        const float* LW1 = swt + 801; const float* LB1 = swt + 881;
        const float* LW2 = swt + 897; float LB2 = swt[913];
        float in5[5] = { bi.x, bi.y, bi.z, bi.w, si };
        float acc = LB2;
        #pragma unroll
        for (int o = 0; o < 16; o++) {
            float a2 = LB1[o];
            #pragma unroll
            for (int f = 0; f < 5; f++) a2 += in5[f] * LW1[f * 16 + o];
            acc += fmaxf(a2, 0.0f) * LW2[o];
        }
        float lam = 1.0f / (1.0f + expf(-acc));
        ((float4*)p.out_boxes)[r] = bi;
        p.out_cls[r] = (float)scls[r];
        p.out_scores[r] = si * expf(-lam * Ssum[tid] * Drow[tid]);
    }
}

extern "C" void kernel_launch(void* const* d_in, const int* in_sizes, int n_in,
                              void* d_out, int out_size, void* d_ws, size_t ws_size,
                              hipStream_t stream) {
    int M = in_sizes[1];
    int K = (M < TOPK) ? M : TOPK;

    char* ws = (char*)d_ws;
    float4* sel_box   = (float4*)ws;           ws += (size_t)TOPK * 16;
    float*  sel_score = (float*)ws;            ws += (size_t)TOPK * 4;
    int*    sel_cls   = (int*)ws;              ws += (size_t)TOPK * 4;

    SelP sp;
    sp.scores  = (const float*)d_in[1];
    sp.boxes   = (const float*)d_in[0];
    sp.classes = (const int*)d_in[2];
    sp.M = M; sp.K = K;
    sp.sel_box = sel_box; sp.sel_score = sel_score; sp.sel_cls = sel_cls;

    CmpP cp;
    cp.sel_box = sel_box; cp.sel_score = sel_score; cp.sel_cls = sel_cls;
    cp.sw1 = (const float*)d_in[3];  cp.sb1 = (const float*)d_in[4];
    cp.sw2 = (const float*)d_in[5];  cp.sb2 = (const float*)d_in[6];
    cp.sw3 = (const float*)d_in[7];  cp.sb3 = (const float*)d_in[8];
    cp.lw1 = (const float*)d_in[9];  cp.lb1 = (const float*)d_in[10];
    cp.lw2 = (const float*)d_in[11]; cp.lb2 = (const float*)d_in[12];
    cp.K = K;
    cp.out_boxes  = (float*)d_out;
    cp.out_scores = (float*)d_out + (size_t)K * 4;
    cp.out_cls    = (float*)d_out + (size_t)K * 5;

    k_sel<<<K1B, STN, 0, stream>>>(sp);
    k_cmp<<<(K + CROWS - 1) / CROWS, CTN, 0, stream>>>(cp);
}

// Round 12
// 110.425 us; speedup vs baseline: 2.1177x; 1.0195x over previous
//
#include <hip/hip_runtime.h>
#include <math.h>

#define TOPK 2048
#define NCLS 80      // reference: randint(0, 80)
#define NBIN 4096    // score-digest bins (uniform scores -> ~5/bin)
#define CMAX 2560    // candidate key capacity (K + tie-bin slack)
#define SMAX 20480   // LDS score-cache capacity (M = 20000 in reference)
#define K1B  32      // selection blocks (candidate partition by idx & 31)
#define STN  1024    // k_sel threads (16 waves)
#define CTN  256     // k_cmp threads
#define CROWS 8      // k_cmp rows per block -> 256 blocks (1 per CU)

struct SelP {
    const float* scores; const float* boxes; const int* classes;
    int M; int K;
    float4* sel_box; float* sel_score; int* sel_cls;
};

struct CmpP {
    const float4* sel_box; const float* sel_score; const int* sel_cls;
    const float* sw1; const float* sb1; const float* sw2; const float* sb2;
    const float* sw3; const float* sb3;
    const float* lw1; const float* lb1; const float* lw2; const float* lb2;
    int K;
    float* out_boxes; float* out_scores; float* out_cls;
};

__device__ __forceinline__ float iou_of(float xi, float yi, float ai,
                                        float x2i, float y2i, float4 bj) {
    float ix1 = fmaxf(xi, bj.x), iy1 = fmaxf(yi, bj.y);
    float ix2 = fminf(x2i, bj.x + bj.z), iy2 = fminf(y2i, bj.y + bj.w);
    float iw = fmaxf(ix2 - ix1, 0.0f), ih = fmaxf(iy2 - iy1, 0.0f);
    float inter = iw * ih;
    float uni = ai + bj.z * bj.w - inter;
    return inter / (uni + 1e-6f);
}

// monotone non-decreasing digest; single quantization used in all passes
__device__ __forceinline__ int digest12(float s) {
    int v = (int)(s * 4096.0f);
    return v < 0 ? 0 : (v > NBIN - 1 ? NBIN - 1 : v);
}

__device__ __forceinline__ float key_score(unsigned long long kk) {
    unsigned mono = (unsigned)(kk >> 32);
    unsigned ob = (mono & 0x80000000u) ? (mono & 0x7FFFFFFFu) : ~mono;
    return __uint_as_float(ob);
}

// ---------------------------------------------------------------------------
// k_sel: 32 blocks redundantly find the exact top-K (jax.lax.top_k stable
// semantics) via binned counting-rank, entirely in LDS after ONE global
// score sweep. Suffix scan is shuffle-based (3 barriers, not 20). Each
// block gathers+writes only candidates whose ORIGINAL index satisfies
// (idx & 31) == bid -- deterministic disjoint partition.
// ---------------------------------------------------------------------------
__global__ __launch_bounds__(STN, 1) void k_sel(SelP p) {
    __shared__ float ssc[SMAX];                   // 80 KB score cache
    __shared__ int   bincur[NBIN];                // 16 KB count -> cursor
    __shared__ int   binbase[NBIN];               // 16 KB rank base
    __shared__ unsigned long long skeys[CMAX];    // 20 KB candidate keys
    __shared__ int   sfx[STN];                    // 4 KB inclusive suffix sums
    __shared__ int   wsum[STN / 64];              // wave-total suffix sums
    __shared__ int   sh_cT;

    int tid = threadIdx.x, bid = blockIdx.x;
    int M = p.M, K = p.K, M4 = M >> 2;

    for (int b = tid; b < NBIN; b += STN) bincur[b] = 0;
    __syncthreads();

    // ---- sweep 1 (the only full global pass): cache scores + histogram ----
    const float4* s4p = (const float4*)p.scores;
    for (int i4 = tid; i4 < M4; i4 += STN) {
        float4 v = s4p[i4];
        if (i4 < SMAX / 4) ((float4*)ssc)[i4] = v;
        atomicAdd(&bincur[digest12(v.x)], 1);
        atomicAdd(&bincur[digest12(v.y)], 1);
        atomicAdd(&bincur[digest12(v.z)], 1);
        atomicAdd(&bincur[digest12(v.w)], 1);
    }
    for (int i = M4 * 4 + tid; i < M; i += STN) {
        float s = p.scores[i];
        if (i < SMAX) ssc[i] = s;
        atomicAdd(&bincur[digest12(s)], 1);
    }
    __syncthreads();

    // ---- suffix scan (shuffle-based): sfx[t] = sum of chunk sums t.. ----
    {
        const int BPT = NBIN / STN;               // 4 bins per thread
        int c0 = tid * BPT, sum = 0;
        #pragma unroll
        for (int u = 0; u < BPT; u++) sum += bincur[c0 + u];
        int lane = tid & 63;
        int x = sum;
        #pragma unroll
        for (int off = 1; off < 64; off <<= 1) {  // in-wave inclusive suffix
            int v = __shfl_down(x, off, 64);
            if (lane + off < 64) x += v;
        }
        if (lane == 0) wsum[tid >> 6] = x;        // wave totals (16)
        __syncthreads();
        if (tid < STN / 64) {                     // suffix over wave totals
            int t = wsum[tid];
            #pragma unroll
            for (int off = 1; off < STN / 64; off <<= 1) {
                int v = __shfl_down(t, off, 64);
                if (tid + off < STN / 64) t += v;
            }
            wsum[tid] = t;
        }
        __syncthreads();
        int wid = tid >> 6;
        int higher = (wid < STN / 64 - 1) ? wsum[wid + 1] : 0;
        sfx[tid] = x + higher;                    // global inclusive suffix
    }
    __syncthreads();

    // ---- binbase per bin + find crossing bin cT ----
    {
        const int BPT = NBIN / STN;
        int running = (tid < STN - 1) ? sfx[tid + 1] : 0;
        int c0 = tid * BPT;
        for (int u = BPT - 1; u >= 0; u--) {
            int b = c0 + u, cnt = bincur[b];
            binbase[b] = running;
            if (running < K && running + cnt >= K) sh_cT = b;  // unique bin
            running += cnt;
        }
    }
    __syncthreads();
    int cT = sh_cT;
    for (int b = tid; b < NBIN; b += STN) bincur[b] = binbase[b];
    __syncthreads();

    // ---- sweep 2 (from LDS): scatter candidate keys into bin slots ----
    // key = monotonic(score bits) << 32 | (0xFFFFFFFF - i): descending key ==
    // descending score, ties -> lower index (stable top_k semantics).
    for (int i = tid; i < M; i += STN) {
        float s = (i < SMAX) ? ssc[i] : p.scores[i];
        int d = digest12(s);
        if (d >= cT) {
            int slot = atomicAdd(&bincur[d], 1);
            if (slot < CMAX) {
                unsigned b = __float_as_uint(s);
                b = (b & 0x80000000u) ? ~b : (b | 0x80000000u);
                skeys[slot] = ((unsigned long long)b << 32) |
                              (unsigned long long)(0xFFFFFFFFu - (unsigned)i);
            }
        }
    }
    __syncthreads();

    // ---- exact rank within bin (~5 peers) + gather/write own partition ----
    {
        int C = bincur[cT]; if (C > CMAX) C = CMAX;
        const float4* boxes4 = (const float4*)p.boxes;
        for (int s = tid; s < C; s += STN) {
            unsigned long long ks = skeys[s];
            unsigned idx = 0xFFFFFFFFu - (unsigned)(ks & 0xFFFFFFFFull);
            if ((int)(idx & (K1B - 1)) != bid) continue;   // partition by index
            float sc = key_score(ks);
            int d = digest12(sc);
            int st = binbase[d], en = bincur[d]; if (en > CMAX) en = CMAX;
            int r = binbase[d];
            for (int t = st; t < en; t++) r += (skeys[t] > ks) ? 1 : 0;
            if (r < K) {
                p.sel_box[r] = boxes4[idx];
                p.sel_score[r] = sc;
                p.sel_cls[r] = p.classes[idx];
            }
        }
    }
}

// ---------------------------------------------------------------------------
// k_cmp: 256 blocks x 8 rows (one block per CU). Stages the 56 KB selected
// arrays into LDS once per block, builds class lists (parallel prefix),
// computes D (unmasked IoU mean, 32 threads/row), S (flat per-pair MLP),
// lambda, and writes this block's outputs.
// ---------------------------------------------------------------------------
__global__ __launch_bounds__(CTN, 1) void k_cmp(CmpP p) {
    __shared__ float4 sbox[TOPK];                 // 32 KB
    __shared__ float  sscore[TOPK];               // 8 KB
    __shared__ short  scls[TOPK];                 // 4 KB
    __shared__ short  clist[TOPK];                // 4 KB
    __shared__ int    ccnt[NCLS], ccur[NCLS], cstart[NCLS + 1];
    __shared__ float  swt[914];                   // sup MLP 801 + lambda 113
    __shared__ int    prefix[CROWS + 1];
    __shared__ int    rowcs[CROWS];
    __shared__ float  Ssum[CROWS], Drow[CROWS];

    int tid = threadIdx.x, bid = blockIdx.x;
    int K = p.K;

    // ---- stage selected arrays first (longest-latency loads) ----
    for (int r = tid; r < K; r += CTN) {
        sbox[r] = p.sel_box[r];
        sscore[r] = p.sel_score[r];
        scls[r] = (short)p.sel_cls[r];
    }

    // ---- stage MLP weights ----
    for (int t = tid; t < 224; t += CTN) swt[t] = p.sw1[t];
    if (tid < 32) swt[224 + tid] = p.sb1[tid];
    for (int t = tid; t < 512; t += CTN) swt[256 + t] = p.sw2[t];
    if (tid < 16) swt[768 + tid] = p.sb2[tid];
    if (tid < 16) swt[784 + tid] = p.sw3[tid];
    if (tid == 0) swt[800] = p.sb3[0];
    if (tid < 80) swt[801 + tid] = p.lw1[tid];
    if (tid < 16) swt[881 + tid] = p.lb1[tid];
    if (tid < 16) swt[897 + tid] = p.lw2[tid];
    if (tid == 0) swt[913] = p.lb2[0];
    if (tid < NCLS) ccnt[tid] = 0;
    __syncthreads();

    // ---- per-class lists (order within class irrelevant: sums) ----
    for (int r = tid; r < K; r += CTN) atomicAdd(&ccnt[scls[r]], 1);
    __syncthreads();
    if (tid < NCLS) {                             // parallel prefix (80 ind. sums)
        int acc = 0;
        for (int u = 0; u < tid; u++) acc += ccnt[u];
        cstart[tid] = acc;
        ccur[tid] = acc;
    }
    if (tid == 0) cstart[NCLS] = K;
    __syncthreads();
    for (int r = tid; r < K; r += CTN) {
        int pos = atomicAdd(&ccur[scls[r]], 1);
        clist[pos] = (short)r;
    }

    int r0 = bid * CROWS;
    int nrows = K - r0; if (nrows > CROWS) nrows = CROWS;
    if (nrows <= 0) return;
    if (tid < nrows) Ssum[tid] = 0.0f;
    __syncthreads();

    // ---- Phase A: D row means; 32 threads/row, 64 cols each ----
    {
        int row = tid >> 5, sub = tid & 31;
        if (row < nrows) {
            float4 bi = sbox[r0 + row];
            float ai = bi.z * bi.w, x2i = bi.x + bi.z, y2i = bi.y + bi.w;
            float dsum = 0.0f;
            for (int j = sub; j < K; j += 32)
                dsum += iou_of(bi.x, bi.y, ai, x2i, y2i, sbox[j]);
            #pragma unroll
            for (int off = 16; off >= 1; off >>= 1)
                dsum += __shfl_xor(dsum, off, 64);
            if (sub == 0) Drow[row] = dsum / (float)K;
        }
    }

    // ---- per-row pair prefix (same-class peer counts; tiny: 8 rows) ----
    if (tid == 0) {
        int acc = 0;
        for (int rr = 0; rr < nrows; rr++) {
            int c = scls[r0 + rr];
            prefix[rr] = acc;
            rowcs[rr] = cstart[c];
            acc += ccnt[c];
        }
        prefix[nrows] = acc;
    }
    __syncthreads();
    int Pb = prefix[nrows];

    const float* W1 = swt;       const float* B1 = swt + 224;
    const float* W2 = swt + 256; const float* B2 = swt + 768;
    const float* W3 = swt + 784; float B3 = swt[800];

    // ---- Phase B: flat per-pair MLP, full lane utilization ----
    for (int pp = tid; pp < Pb; pp += CTN) {
        int lo = 0, hi = nrows;
        while (hi - lo > 1) {
            int mid = (lo + hi) >> 1;
            if (prefix[mid] <= pp) lo = mid; else hi = mid;
        }
        int row = lo;
        int j = clist[rowcs[row] + (pp - prefix[row])];
        float4 bi = sbox[r0 + row], bj = sbox[j];
        float ai = bi.z * bi.w, x2i = bi.x + bi.z, y2i = bi.y + bi.w;
        float iou = iou_of(bi.x, bi.y, ai, x2i, y2i, bj);
        float f1 = fabsf(bi.x - bj.x), f2 = fabsf(bi.y - bj.y);
        float f3 = fabsf(bi.z - bj.z), f4 = fabsf(bi.w - bj.w);
        float f5 = sscore[r0 + row], f6 = sscore[j];
        float h[32];
        #pragma unroll
        for (int o = 0; o < 32; o++) {
            float a = B1[o];
            a += iou * W1[0 * 32 + o];
            a += f1 * W1[1 * 32 + o];
            a += f2 * W1[2 * 32 + o];
            a += f3 * W1[3 * 32 + o];
            a += f4 * W1[4 * 32 + o];
            a += f5 * W1[5 * 32 + o];
            a += f6 * W1[6 * 32 + o];
            h[o] = fmaxf(a, 0.0f);
        }
        float acc3 = B3;
        #pragma unroll
        for (int q = 0; q < 16; q++) {
            float a = B2[q];
            #pragma unroll
            for (int o = 0; o < 32; o++) a += h[o] * W2[o * 16 + q];
            acc3 += fmaxf(a, 0.0f) * W3[q];
        }
        atomicAdd(&Ssum[row], iou / (1.0f + expf(-acc3)));
    }
    __syncthreads();

    // ---- finale: lambda MLP + outputs for this block's rows ----
    if (tid < nrows) {
        int r = r0 + tid;
        float4 bi = sbox[r];
        float si = sscore[r];
        const float* LW1 = swt + 801; const float* LB1 = swt + 881;
        const float* LW2 = swt + 897; float LB2 = swt[913];
        float in5[5] = { bi.x, bi.y, bi.z, bi.w, si };
        float acc = LB2;
        #pragma unroll
        for (int o = 0; o < 16; o++) {
            float a2 = LB1[o];
            #pragma unroll
            for (int f = 0; f < 5; f++) a2 += in5[f] * LW1[f * 16 + o];
            acc += fmaxf(a2, 0.0f) * LW2[o];
        }
        float lam = 1.0f / (1.0f + expf(-acc));
        ((float4*)p.out_boxes)[r] = bi;
        p.out_cls[r] = (float)scls[r];
        p.out_scores[r] = si * expf(-lam * Ssum[tid] * Drow[tid]);
    }
}

extern "C" void kernel_launch(void* const* d_in, const int* in_sizes, int n_in,
                              void* d_out, int out_size, void* d_ws, size_t ws_size,
                              hipStream_t stream) {
    int M = in_sizes[1];
    int K = (M < TOPK) ? M : TOPK;

    char* ws = (char*)d_ws;
    float4* sel_box   = (float4*)ws;           ws += (size_t)TOPK * 16;
    float*  sel_score = (float*)ws;            ws += (size_t)TOPK * 4;
    int*    sel_cls   = (int*)ws;              ws += (size_t)TOPK * 4;

    SelP sp;
    sp.scores  = (const float*)d_in[1];
    sp.boxes   = (const float*)d_in[0];
    sp.classes = (const int*)d_in[2];
    sp.M = M; sp.K = K;
    sp.sel_box = sel_box; sp.sel_score = sel_score; sp.sel_cls = sel_cls;

    CmpP cp;
    cp.sel_box = sel_box; cp.sel_score = sel_score; cp.sel_cls = sel_cls;
    cp.sw1 = (const float*)d_in[3];  cp.sb1 = (const float*)d_in[4];
    cp.sw2 = (const float*)d_in[5];  cp.sb2 = (const float*)d_in[6];
    cp.sw3 = (const float*)d_in[7];  cp.sb3 = (const float*)d_in[8];
    cp.lw1 = (const float*)d_in[9];  cp.lb1 = (const float*)d_in[10];
    cp.lw2 = (const float*)d_in[11]; cp.lb2 = (const float*)d_in[12];
    cp.K = K;
    cp.out_boxes  = (float*)d_out;
    cp.out_scores = (float*)d_out + (size_t)K * 4;
    cp.out_cls    = (float*)d_out + (size_t)K * 5;

    k_sel<<<K1B, STN, 0, stream>>>(sp);
    k_cmp<<<(K + CROWS - 1) / CROWS, CTN, 0, stream>>>(cp);
}